// Round 2
// 441.971 us; speedup vs baseline: 1.0087x; 1.0087x over previous
//
#include <hip/hip_runtime.h>
#include <hip/hip_bf16.h>
#include <math.h>

typedef __bf16 bf16;
typedef __bf16 bf16x8 __attribute__((ext_vector_type(8)));
typedef __bf16 bf16x4 __attribute__((ext_vector_type(4)));
typedef float  f32x4  __attribute__((ext_vector_type(4)));
typedef short  sv4    __attribute__((ext_vector_type(4)));

#define B_  2
#define T_  2048
#define DM  2048
#define H_  32
#define DH  64

__device__ __forceinline__ bf16x8 load8(const bf16* p) {
    return *reinterpret_cast<const bf16x8*>(p);
}

__device__ __forceinline__ void gld16(const bf16* g, bf16* l) {
    __builtin_amdgcn_global_load_lds(
        (const __attribute__((address_space(1))) unsigned int*)g,
        (__attribute__((address_space(3))) unsigned int*)l, 16, 0, 0);
}

// ---------------- convert fp32 -> bf16 ----------------
__global__ void k_convert(const float* __restrict__ in, bf16* __restrict__ out, int n4) {
    int i = blockIdx.x * blockDim.x + threadIdx.x;
    if (i < n4) {
        float4 v = reinterpret_cast<const float4*>(in)[i];
        bf16x4 o;
        o[0] = (bf16)v.x; o[1] = (bf16)v.y; o[2] = (bf16)v.z; o[3] = (bf16)v.w;
        reinterpret_cast<bf16x4*>(out)[i] = o;
    }
}

// ---------------- transpose + convert weights ----------------
__global__ void k_transposeW(const float* __restrict__ Wq, const float* __restrict__ Wk,
                             const float* __restrict__ Wv, const float* __restrict__ Wo,
                             bf16* __restrict__ WqT, bf16* __restrict__ WkT,
                             bf16* __restrict__ WvT, bf16* __restrict__ WoT) {
    const float* in; bf16* out;
    switch (blockIdx.z) {
        case 0: in = Wq; out = WqT; break;
        case 1: in = Wk; out = WkT; break;
        case 2: in = Wv; out = WvT; break;
        default: in = Wo; out = WoT; break;
    }
    __shared__ float tile[32][33];
    int tx = threadIdx.x, ty = threadIdx.y;
    int x0 = blockIdx.x * 32, y0 = blockIdx.y * 32;
    #pragma unroll
    for (int i = 0; i < 4; i++)
        tile[ty + i*8][tx] = in[(size_t)(y0 + ty + i*8) * DM + x0 + tx];
    __syncthreads();
    #pragma unroll
    for (int i = 0; i < 4; i++)
        out[(size_t)(x0 + ty + i*8) * DM + y0 + tx] = (bf16)tile[tx][ty + i*8];
}

// ---------------- m97-style GEMM, XOR-swizzled LDS (conflict-free) -----------
// Kept for the out-projection (M=4096,N=2048 -> 512 blocks of 128x128 fills
// all CUs; a 256^2 tiling would give only 128 blocks = half the chip idle).
template<int OUT_BF16>
__global__ __launch_bounds__(256)
void k_gemm(const bf16* __restrict__ A, const bf16* __restrict__ BT,
            void* __restrict__ Cout, int ldc) {
    constexpr int K = 2048;
    __shared__ bf16 ldsA[128 * 32];
    __shared__ bf16 ldsB[128 * 32];
    int tid = threadIdx.x;
    int lane = tid & 63, w = tid >> 6;
    int l16 = lane & 15, quad = lane >> 4;
    int wm = w >> 1, wn = w & 1;
    int mblk = blockIdx.y * 128, nblk = blockIdx.x * 128;

    f32x4 acc[4][4] = {};

    int sgz = ((lane & 3) ^ ((lane >> 3) & 3)) * 8;      // swizzled global seg
    const bf16* gA = A  + (size_t)(mblk + w * 32 + (lane >> 2)) * K + sgz;
    const bf16* gB = BT + (size_t)(nblk + w * 32 + (lane >> 2)) * K + sgz;
    bf16* lA = ldsA + w * 1024;
    bf16* lB = ldsB + w * 1024;
    int sA = (quad ^ ((l16 >> 1) & 3)) * 8;              // swizzled read seg

    for (int k0 = 0; k0 < K; k0 += 32) {
        gld16(gA + k0,          lA);
        gld16(gA + 16 * K + k0, lA + 512);
        gld16(gB + k0,          lB);
        gld16(gB + 16 * K + k0, lB + 512);
        __syncthreads();
        bf16x8 af[4], bfr[4];
        #pragma unroll
        for (int s = 0; s < 4; s++)
            af[s] = *reinterpret_cast<bf16x8*>(&ldsA[(wm * 64 + s * 16 + l16) * 32 + sA]);
        #pragma unroll
        for (int t = 0; t < 4; t++)
            bfr[t] = *reinterpret_cast<bf16x8*>(&ldsB[(wn * 64 + t * 16 + l16) * 32 + sA]);
        #pragma unroll
        for (int s = 0; s < 4; s++)
            #pragma unroll
            for (int t = 0; t < 4; t++)
                acc[s][t] = __builtin_amdgcn_mfma_f32_16x16x32_bf16(af[s], bfr[t], acc[s][t], 0, 0, 0);
        __syncthreads();
    }

    #pragma unroll
    for (int s = 0; s < 4; s++) {
        int row = mblk + wm * 64 + s * 16 + quad * 4;
        #pragma unroll
        for (int t = 0; t < 4; t++) {
            int col = nblk + wn * 64 + t * 16 + l16;
            #pragma unroll
            for (int r = 0; r < 4; r++) {
                if (OUT_BF16)
                    reinterpret_cast<bf16*>(Cout)[(size_t)(row + r) * ldc + col] = (bf16)acc[s][t][r];
                else
                    reinterpret_cast<float*>(Cout)[(size_t)(row + r) * ldc + col] = acc[s][t][r];
            }
        }
    }
}

// ---------------- 256x256 phase-split GEMM, BK=32, 64 KiB STATIC LDS --------
// m201-equivalent schedule density without dynamic-LDS opt-in (which needs
// hipFuncSetAttribute -> unsafe under the harness's graph capture).
// 512 thr = 8 waves (2m x 4n), per-wave output 128x64, acc[8][4].
// LDS: 2 buffers x {B: 256x32 (16K), A: 256x32 (16K)} = 64 KiB.
// Per K-tile (BK=32), 2 phases x 16 MFMA:
//   ph0: ds_read A-mh0 (4xb128) + B (4xb128); stage A(t+1) -> other buf;
//        BAR; setprio1; 16 MFMA; setprio0; BAR
//   ph1: ds_read A-mh1; stage B(t+2) -> this buf's B (read-complete since
//        ph0+barrier); BAR; setprio1; 16 MFMA; setprio0; vmcnt(2); BAR
// Counted vmcnt(2) once per tile = exactly next tile's B-prefetch in flight;
// wait-then-barrier makes every wave's staging visible to all. Tail peeled:
// vmcnt(0) at tile 62, compute-only tile 63.
// Rows 32 bf16 (64B); 16B segs XOR-swizzled by (row>>1)&3 (linear gld_lds
// dest + inverse-swizzled global src + swizzled ds_read) -> conflict-free.
template<int OUT_BF16>
__global__ __launch_bounds__(512, 2)
void k_gemm256(const bf16* __restrict__ A, const bf16* __restrict__ BT,
               void* __restrict__ Cout, int ldc) {
    constexpr int K = 2048;
    __shared__ bf16 lds[32768];                     // 64 KiB
    const int tid  = threadIdx.x;
    const int lane = tid & 63, w = tid >> 6;
    const int l16  = lane & 15, quad = lane >> 4;
    const int wm   = w >> 2, wn = w & 3;
    const size_t mblk = (size_t)blockIdx.y * 256, nblk = (size_t)blockIdx.x * 256;

    f32x4 acc[8][4] = {};

    // staging: thread covers row (tid>>2) (+128 for 2nd load), 16B seg.
    // stored seg = tid&3 (lane-linear) -> fetch logical seg (tid&3)^((row>>1)&3).
    const int sg = (((tid & 3) ^ ((tid >> 3) & 3)) << 3);
    const bf16* gA = A  + (mblk + (tid >> 2)) * K + sg;
    const bf16* gB = BT + (nblk + (tid >> 2)) * K + sg;

    // fragment reads: row = base+l16 (base mult of 16), logical seg = quad.
    const int segr = ((quad ^ ((l16 >> 1) & 3)) << 3);
    const int aoff = (wm * 128 + l16) * 32 + segr;  // A region (+8192 in buf)
    const int boff = (wn * 64  + l16) * 32 + segr;  // B region (+0 in buf)

    // buf c at element offset c*16384; B at +0, A at +8192.
#define STGA(kt_) do { \
    const bf16* g_ = gA + (kt_) * 32; \
    bf16* l_ = lds + ((((kt_) & 1) << 14) + 8192) + w * 512; \
    gld16(g_, l_); gld16(g_ + 128 * 2048, l_ + 4096); \
} while (0)

#define STGB(kt_) do { \
    const bf16* g_ = gB + (kt_) * 32; \
    bf16* l_ = lds + (((kt_) & 1) << 14) + w * 512; \
    gld16(g_, l_); gld16(g_ + 128 * 2048, l_ + 4096); \
} while (0)

#define LD4(dst_, base_) do { \
    _Pragma("unroll") for (int i_ = 0; i_ < 4; ++i_) \
        dst_[i_] = *reinterpret_cast<const bf16x8*>((base_) + i_ * 512); \
} while (0)

#define MFMA16(mh_) do { \
    _Pragma("unroll") for (int mi_ = 0; mi_ < 4; ++mi_) \
        _Pragma("unroll") for (int ni_ = 0; ni_ < 4; ++ni_) \
            acc[(mh_) * 4 + mi_][ni_] = __builtin_amdgcn_mfma_f32_16x16x32_bf16( \
                af[mi_], bq[ni_], acc[(mh_) * 4 + mi_][ni_], 0, 0, 0); \
} while (0)

#define BAR  __builtin_amdgcn_s_barrier()
#define PRI1 __builtin_amdgcn_s_setprio(1)
#define PRI0 __builtin_amdgcn_s_setprio(0)
#define VM2  asm volatile("s_waitcnt vmcnt(2)" ::: "memory")
#define VM0  asm volatile("s_waitcnt vmcnt(0)" ::: "memory")

#define TILE(cb_, S0_, S1_, VM_) do { \
    const bf16* rb_ = lds + (cb_) + boff; \
    const bf16* ra_ = lds + (cb_) + 8192 + aoff; \
    bf16x8 af[4], bq[4]; \
    LD4(af, ra_); LD4(bq, rb_); \
    S0_; BAR; PRI1; MFMA16(0); PRI0; BAR; \
    LD4(af, ra_ + 2048); \
    S1_; BAR; PRI1; MFMA16(1); PRI0; VM_; BAR; \
} while (0)

    // prologue: B0, A0 (tile0 complete) + B1 prefetch; allow B1 outstanding.
    STGB(0); STGA(0); STGB(1);
    VM2;
    BAR;

    #pragma unroll 1
    for (int t = 0; t < 61; t += 2) {
        TILE(0,     STGA(t + 1), STGB(t + 2), VM2);
        TILE(16384, STGA(t + 2), STGB(t + 3), VM2);
    }
    // tile 62 (buf0): stage A(63) only; drain fully before last tile.
    TILE(0,     STGA(63), (void)0, VM0);
    // tile 63 (buf1): compute only.
    TILE(16384, (void)0, (void)0, (void)0);

#undef STGA
#undef STGB
#undef LD4
#undef MFMA16
#undef BAR
#undef PRI1
#undef PRI0
#undef VM2
#undef VM0
#undef TILE

    #pragma unroll
    for (int mt = 0; mt < 8; ++mt) {
        size_t row = mblk + wm * 128 + mt * 16 + quad * 4;
        #pragma unroll
        for (int nt = 0; nt < 4; ++nt) {
            size_t col = nblk + wn * 64 + nt * 16 + l16;
            #pragma unroll
            for (int r = 0; r < 4; ++r) {
                if (OUT_BF16)
                    reinterpret_cast<bf16*>(Cout)[(row + r) * (size_t)ldc + col] = (bf16)acc[mt][nt][r];
                else
                    reinterpret_cast<float*>(Cout)[(row + r) * (size_t)ldc + col] = acc[mt][nt][r];
            }
        }
    }
}

// ---------------- RoPE cos/sin table: tab[t*32+i] = (cos, sin)(t * 10000^(-i/32))
__global__ void k_tab(float2* __restrict__ tab) {
    int id = blockIdx.x * 256 + threadIdx.x;   // 65536
    int i = id & 31, t = id >> 5;
    float inv = __builtin_amdgcn_exp2f(-(float)i * 0.41524101186092037f);
    float ang = (float)t * inv;
    float s, c;
    __sincosf(ang, &s, &c);
    tab[id] = make_float2(c, s);
}

// ---------------- RoPE apply, vectorized, table-based ------------------------
__global__ void k_rope(bf16* __restrict__ qkv, const float2* __restrict__ tab) {
    int id = blockIdx.x * 256 + threadIdx.x;   // 2^20 threads
    int j   = id & 3;
    int h   = (id >> 2) & 31;
    int sel = (id >> 7) & 1;
    int t   = (id >> 8) & 2047;
    int b   = id >> 19;
    size_t base = ((size_t)(b * T_ + t)) * 6144 + sel * 2048 + h * 64 + j * 8;
    bf16x8 x1 = load8(qkv + base);
    bf16x8 x2 = load8(qkv + base + 32);
    const float2* tp = tab + t * 32 + j * 8;
    bf16x8 o1, o2;
    #pragma unroll
    for (int e = 0; e < 8; e++) {
        float c = tp[e].x, s = tp[e].y;
        float a = (float)x1[e], v = (float)x2[e];
        o1[e] = (bf16)(a * c - v * s);
        o2[e] = (bf16)(v * c + a * s);
    }
    *reinterpret_cast<bf16x8*>(qkv + base)      = o1;
    *reinterpret_cast<bf16x8*>(qkv + base + 32) = o2;
}

// ---------------- v = l1*v1 + l2*v_gemm -> vT [B,H,DH,T] bf16 ----------------
__global__ void k_combinev(const float* __restrict__ v1, const bf16* __restrict__ qkv,
                           const float* __restrict__ l1p, const float* __restrict__ l2p,
                           bf16* __restrict__ vT) {
    __shared__ float tile[64 * 33];
    float l1 = l1p[0], l2 = l2p[0];
    int b = blockIdx.y >> 5, h = blockIdx.y & 31;
    int t0 = blockIdx.x * 32;
    int tid = threadIdx.x;
    int d = tid & 63, tr = tid >> 6;
    #pragma unroll
    for (int i = 0; i < 8; i++) {
        int t = t0 + i * 4 + tr;
        size_t iv1 = ((size_t)(b * T_ + t)) * 2048 + h * 64 + d;
        size_t ivg = ((size_t)(b * T_ + t)) * 6144 + 4096 + h * 64 + d;
        tile[d * 33 + i * 4 + tr] = l1 * v1[iv1] + l2 * (float)qkv[ivg];
    }
    __syncthreads();
    int tl = tid & 31, dr = tid >> 5;
    #pragma unroll
    for (int j = 0; j < 8; j++) {
        int d2 = dr + j * 8;
        vT[((size_t)((b * H_ + h) * 64 + d2)) * T_ + t0 + tl] = (bf16)tile[d2 * 33 + tl];
    }
}

// ---------------- causal flash attention, S^T form ----------------
__global__ __launch_bounds__(256)
void k_attn(const bf16* __restrict__ qkv, const bf16* __restrict__ vT, bf16* __restrict__ o) {
    __shared__ bf16 ldsK[64 * 64];   // [key][dh], swizzled
    __shared__ bf16 ldsV[64 * 64];   // [dh][key], swizzled
    int bx = blockIdx.x;             // 0..15
    int bh = blockIdx.y;
    int b = bh >> 5, h = bh & 31;
    int tid = threadIdx.x;
    int lane = tid & 63, w = tid >> 6;
    int l16 = lane & 15, quad = lane >> 4;

    int rl = lane >> 3, sg = ((lane & 7) ^ rl) * 8;
    const bf16* kgl = qkv + ((size_t)(b * T_) + w * 16 + rl) * 6144 + 2048 + h * 64 + sg;
    const bf16* vgl = vT + ((size_t)bh * DH + w * 16 + rl) * T_ + sg;
    bf16* lKw = ldsK + w * 16 * 64;
    bf16* lVw = ldsV + w * 16 * 64;

    int skey = (quad ^ (l16 & 7)) * 8;            // K read seg, dh 0..31
    int skey2 = ((quad + 4) ^ (l16 & 7)) * 8;     // K read seg, dh 32..63

    #pragma unroll 1
    for (int pass = 0; pass < 2; pass++) {
        int qt = pass ? (31 - bx) : bx;
        int qbase = qt * 64 + w * 16;

        size_t qrow = (size_t)(b * T_ + qbase + l16) * 6144 + h * 64;
        bf16x8 qf[2];
        #pragma unroll
        for (int half = 0; half < 2; half++) {
            bf16x8 v = load8(qkv + qrow + half * 32 + quad * 8);
            #pragma unroll
            for (int e = 0; e < 8; e++) v[e] = (bf16)((float)v[e] * 0.1803368801f);
            qf[half] = v;
        }

        f32x4 accO[4] = {};
        float m_ = -1e30f, pl = 0.f;

        int nkt = qt + 1;
        for (int kt = 0; kt < nkt; kt++) {
            int key0 = kt * 64;
            #pragma unroll
            for (int j = 0; j < 2; j++) {
                gld16(kgl + (size_t)(key0 + j * 8) * 6144, lKw + j * 512);
                gld16(vgl + (size_t)(j * 8) * T_ + key0,   lVw + j * 512);
            }
            __syncthreads();

            bool diag = (kt == qt);
            f32x4 st[4];
            sv4 pk[4];
            #pragma unroll
            for (int ks = 0; ks < 4; ks++) {
                if (!diag || key0 + ks * 16 <= qbase + 15) {
                    bf16x8 kf0 = *reinterpret_cast<bf16x8*>(&ldsK[(ks * 16 + l16) * 64 + skey]);
                    bf16x8 kf1 = *reinterpret_cast<bf16x8*>(&ldsK[(ks * 16 + l16) * 64 + skey2]);
                    f32x4 z = {};
                    z = __builtin_amdgcn_mfma_f32_16x16x32_bf16(kf0, qf[0], z, 0, 0, 0);
                    z = __builtin_amdgcn_mfma_f32_16x16x32_bf16(kf1, qf[1], z, 0, 0, 0);
                    st[ks] = z;
                } else {
                    st[ks] = (f32x4){-3e38f, -3e38f, -3e38f, -3e38f};
                }
            }

            if (diag) {
                int qcol = qbase + l16;
                #pragma unroll
                for (int ks = 0; ks < 4; ks++)
                    #pragma unroll
                    for (int r = 0; r < 4; r++)
                        if (key0 + ks * 16 + quad * 4 + r > qcol) st[ks][r] = -3e38f;
            }

            float mx = st[0][0];
            #pragma unroll
            for (int ks = 0; ks < 4; ks++)
                #pragma unroll
                for (int r = 0; r < 4; r++) mx = fmaxf(mx, st[ks][r]);
            mx = fmaxf(mx, __shfl_xor(mx, 16));
            mx = fmaxf(mx, __shfl_xor(mx, 32));
            if (__any(mx > m_)) {
                float nm = fmaxf(m_, mx);
                float alpha = __builtin_amdgcn_exp2f(m_ - nm);
                m_ = nm;
                pl *= alpha;
                #pragma unroll
                for (int n2 = 0; n2 < 4; n2++) accO[n2] *= alpha;
            }
            float rsum = 0.f;
            #pragma unroll
            for (int ks = 0; ks < 4; ks++) {
                bf16x4 ph;
                #pragma unroll
                for (int r = 0; r < 4; r++) {
                    float p = __builtin_amdgcn_exp2f(st[ks][r] - m_);
                    rsum += p;
                    ph[r] = (bf16)p;
                }
                pk[ks] = __builtin_bit_cast(sv4, ph);
            }
            pl += rsum;

            #pragma unroll
            for (int ks = 0; ks < 4; ks++) {
                if (!diag || key0 + ks * 16 <= qbase + 15) {
                    int svf = ((ks * 2 + (quad >> 1)) ^ (l16 & 7)) * 8 + (quad & 1) * 4;
                    #pragma unroll
                    for (int n2 = 0; n2 < 4; n2++) {
                        sv4 vf = *reinterpret_cast<sv4*>(&ldsV[(n2 * 16 + l16) * 64 + svf]);
                        accO[n2] = __builtin_amdgcn_mfma_f32_16x16x16bf16_1k(
                            vf, pk[ks], accO[n2], 0, 0, 0);
                    }
                }
            }
            __syncthreads();
        }

        float l = pl;
        l += __shfl_xor(l, 16);
        l += __shfl_xor(l, 32);
        float inv = 1.0f / l;
        int query = qbase + l16;
        #pragma unroll
        for (int n2 = 0; n2 < 4; n2++) {
            bf16x4 ov;
            #pragma unroll
            for (int r = 0; r < 4; r++) ov[r] = (bf16)(accO[n2][r] * inv);
            *reinterpret_cast<bf16x4*>(
                &o[(size_t)(b * T_ + query) * DM + h * 64 + n2 * 16 + quad * 4]) = ov;
        }
    }
}

extern "C" void kernel_launch(void* const* d_in, const int* in_sizes, int n_in,
                              void* d_out, int out_size, void* d_ws, size_t ws_size,
                              hipStream_t stream) {
    const float* hs   = (const float*)d_in[0];
    const float* v1   = (const float*)d_in[1];
    const float* lam1 = (const float*)d_in[2];
    const float* Wq   = (const float*)d_in[3];
    const float* Wk   = (const float*)d_in[4];
    const float* Wv   = (const float*)d_in[5];
    const float* Wo   = (const float*)d_in[6];
    const float* lam2 = (const float*)d_in[7];

    char* ws = (char*)d_ws;
    bf16* hs_bf = (bf16*)(ws);                            // 16 MiB (dead after QKV gemm)
    float2* tab = (float2*)(ws);                          // 512 KB, reuses hs_bf region
    bf16* Wcat  = (bf16*)(ws + 16777216);                 // WqT|WkT|WvT, 24 MiB
    bf16* WoT   = (bf16*)(ws + 41943040);                 // 8 MiB
    bf16* qkv   = (bf16*)(ws + 50331648);                 // 4096x6144 bf16 = 48 MiB
    bf16* vT_bf = (bf16*)(ws + 100663296);                // 16 MiB
    bf16* o_bf  = (bf16*)(ws + 117440512);                // 16 MiB -> 128 MiB

    k_convert<<<8192, 256, 0, stream>>>(hs, hs_bf, 2097152);
    k_transposeW<<<dim3(64, 64, 4), dim3(32, 8), 0, stream>>>(
        Wq, Wk, Wv, Wo, Wcat, Wcat + 4194304, Wcat + 8388608, WoT);

    // QKV: M=4096, N=6144, K=2048 -> 24x16 = 384 blocks, 256^2 phase-split
    k_gemm256<1><<<dim3(24, 16), 512, 0, stream>>>(hs_bf, Wcat, (void*)qkv, 6144);

    k_tab<<<256, 256, 0, stream>>>(tab);                  // hs_bf dead from here
    k_rope<<<4096, 256, 0, stream>>>(qkv, tab);

    k_combinev<<<dim3(64, 64), 256, 0, stream>>>(v1, qkv, lam1, lam2, vT_bf);

    k_attn<<<dim3(16, 64), 256, 0, stream>>>(qkv, vT_bf, o_bf);

    k_gemm<0><<<dim3(16, 32), 256, 0, stream>>>(o_bf, WoT, d_out, 2048);
}

// Round 3
// 439.960 us; speedup vs baseline: 1.0133x; 1.0046x over previous
//
#include <hip/hip_runtime.h>
#include <hip/hip_bf16.h>
#include <math.h>

typedef __bf16 bf16;
typedef __bf16 bf16x8 __attribute__((ext_vector_type(8)));
typedef __bf16 bf16x4 __attribute__((ext_vector_type(4)));
typedef float  f32x4  __attribute__((ext_vector_type(4)));
typedef short  sv4    __attribute__((ext_vector_type(4)));

#define B_  2
#define T_  2048
#define DM  2048
#define H_  32
#define DH  64

__device__ __forceinline__ bf16x8 load8(const bf16* p) {
    return *reinterpret_cast<const bf16x8*>(p);
}

__device__ __forceinline__ void gld16(const bf16* g, bf16* l) {
    __builtin_amdgcn_global_load_lds(
        (const __attribute__((address_space(1))) unsigned int*)g,
        (__attribute__((address_space(3))) unsigned int*)l, 16, 0, 0);
}

// ---------------- convert fp32 -> bf16 ----------------
__global__ void k_convert(const float* __restrict__ in, bf16* __restrict__ out, int n4) {
    int i = blockIdx.x * blockDim.x + threadIdx.x;
    if (i < n4) {
        float4 v = reinterpret_cast<const float4*>(in)[i];
        bf16x4 o;
        o[0] = (bf16)v.x; o[1] = (bf16)v.y; o[2] = (bf16)v.z; o[3] = (bf16)v.w;
        reinterpret_cast<bf16x4*>(out)[i] = o;
    }
}

// ---------------- transpose + convert weights ----------------
__global__ void k_transposeW(const float* __restrict__ Wq, const float* __restrict__ Wk,
                             const float* __restrict__ Wv, const float* __restrict__ Wo,
                             bf16* __restrict__ WqT, bf16* __restrict__ WkT,
                             bf16* __restrict__ WvT, bf16* __restrict__ WoT) {
    const float* in; bf16* out;
    switch (blockIdx.z) {
        case 0: in = Wq; out = WqT; break;
        case 1: in = Wk; out = WkT; break;
        case 2: in = Wv; out = WvT; break;
        default: in = Wo; out = WoT; break;
    }
    __shared__ float tile[32][33];
    int tx = threadIdx.x, ty = threadIdx.y;
    int x0 = blockIdx.x * 32, y0 = blockIdx.y * 32;
    #pragma unroll
    for (int i = 0; i < 4; i++)
        tile[ty + i*8][tx] = in[(size_t)(y0 + ty + i*8) * DM + x0 + tx];
    __syncthreads();
    #pragma unroll
    for (int i = 0; i < 4; i++)
        out[(size_t)(x0 + ty + i*8) * DM + y0 + tx] = (bf16)tile[tx][ty + i*8];
}

// ---------------- m97-style GEMM, XOR-swizzled LDS (conflict-free) -----------
// Kept for the out-projection (M=4096,N=2048 -> 512 blocks of 128x128 fills
// all CUs; a 256^2 tiling would give only 128 blocks = half the chip idle).
template<int OUT_BF16>
__global__ __launch_bounds__(256)
void k_gemm(const bf16* __restrict__ A, const bf16* __restrict__ BT,
            void* __restrict__ Cout, int ldc) {
    constexpr int K = 2048;
    __shared__ bf16 ldsA[128 * 32];
    __shared__ bf16 ldsB[128 * 32];
    int tid = threadIdx.x;
    int lane = tid & 63, w = tid >> 6;
    int l16 = lane & 15, quad = lane >> 4;
    int wm = w >> 1, wn = w & 1;
    int mblk = blockIdx.y * 128, nblk = blockIdx.x * 128;

    f32x4 acc[4][4] = {};

    int sgz = ((lane & 3) ^ ((lane >> 3) & 3)) * 8;      // swizzled global seg
    const bf16* gA = A  + (size_t)(mblk + w * 32 + (lane >> 2)) * K + sgz;
    const bf16* gB = BT + (size_t)(nblk + w * 32 + (lane >> 2)) * K + sgz;
    bf16* lA = ldsA + w * 1024;
    bf16* lB = ldsB + w * 1024;
    int sA = (quad ^ ((l16 >> 1) & 3)) * 8;              // swizzled read seg

    for (int k0 = 0; k0 < K; k0 += 32) {
        gld16(gA + k0,          lA);
        gld16(gA + 16 * K + k0, lA + 512);
        gld16(gB + k0,          lB);
        gld16(gB + 16 * K + k0, lB + 512);
        __syncthreads();
        bf16x8 af[4], bfr[4];
        #pragma unroll
        for (int s = 0; s < 4; s++)
            af[s] = *reinterpret_cast<bf16x8*>(&ldsA[(wm * 64 + s * 16 + l16) * 32 + sA]);
        #pragma unroll
        for (int t = 0; t < 4; t++)
            bfr[t] = *reinterpret_cast<bf16x8*>(&ldsB[(wn * 64 + t * 16 + l16) * 32 + sA]);
        #pragma unroll
        for (int s = 0; s < 4; s++)
            #pragma unroll
            for (int t = 0; t < 4; t++)
                acc[s][t] = __builtin_amdgcn_mfma_f32_16x16x32_bf16(af[s], bfr[t], acc[s][t], 0, 0, 0);
        __syncthreads();
    }

    #pragma unroll
    for (int s = 0; s < 4; s++) {
        int row = mblk + wm * 64 + s * 16 + quad * 4;
        #pragma unroll
        for (int t = 0; t < 4; t++) {
            int col = nblk + wn * 64 + t * 16 + l16;
            #pragma unroll
            for (int r = 0; r < 4; r++) {
                if (OUT_BF16)
                    reinterpret_cast<bf16*>(Cout)[(size_t)(row + r) * ldc + col] = (bf16)acc[s][t][r];
                else
                    reinterpret_cast<float*>(Cout)[(size_t)(row + r) * ldc + col] = acc[s][t][r];
            }
        }
    }
}

// ---------------- 256x256 deep-lead GEMM, BK=32, 64 KiB STATIC LDS ----------
// Round-2 post-mortem: vmcnt(2) with a 1.5-phase issue-to-wait lead stalled on
// HBM latency every tile (MfmaUtil stuck at 37%). This version reads the WHOLE
// tile's fragments (12 x ds_read_b128) up front, fences with lgkmcnt(0)
// BEFORE the barrier (=> after the barrier the current buffer is fully
// consumed by ALL waves -> same-buffer staging is race-free), then stages
// tile t+2 into this tile's own buffer. Lead = 2 full tiles, vmcnt(4) per
// tile (issue-to-wait ~3-4 phases ~600-800 cyc), never drained in-loop.
// 2 barriers/tile; staging interleaved into the 2x16-MFMA cluster; setprio(1)
// around MFMA (T5). Same XOR seg-swizzle (linear gld_lds dest +
// inverse-swizzled global src + swizzled ds_read) -> conflict-free.
template<int OUT_BF16>
__global__ __launch_bounds__(512, 2)
void k_gemm256(const bf16* __restrict__ A, const bf16* __restrict__ BT,
               void* __restrict__ Cout, int ldc) {
    constexpr int K = 2048;
    __shared__ bf16 lds[32768];                     // 64 KiB: 2 bufs x {B,A} x 16 KB
    const int tid  = threadIdx.x;
    const int lane = tid & 63, w = tid >> 6;
    const int l16  = lane & 15, quad = lane >> 4;
    const int wm   = w >> 2, wn = w & 3;
    const size_t mblk = (size_t)blockIdx.y * 256, nblk = (size_t)blockIdx.x * 256;

    f32x4 acc[8][4] = {};

    // staging: thread covers row (tid>>2) (+128 for 2nd load), 16B seg.
    // stored seg = tid&3 (lane-linear) -> fetch logical seg (tid&3)^((row>>1)&3).
    const int sg = (((tid & 3) ^ ((tid >> 3) & 3)) << 3);
    const bf16* gA = A  + (mblk + (tid >> 2)) * K + sg;
    const bf16* gB = BT + (nblk + (tid >> 2)) * K + sg;

    // fragment reads: row = base+l16 (base mult of 16), logical seg = quad.
    const int segr = ((quad ^ ((l16 >> 1) & 3)) << 3);
    const int aoff = (wm * 128 + l16) * 32 + segr;  // A region (+8192 in buf)
    const int boff = (wn * 64  + l16) * 32 + segr;  // B region (+0 in buf)

    // buf c at element offset c*16384; B at +0, A at +8192.
#define STGA(kt_) do { \
    const bf16* g_ = gA + (kt_) * 32; \
    bf16* l_ = lds + ((((kt_) & 1) << 14) + 8192) + w * 512; \
    gld16(g_, l_); gld16(g_ + 128 * 2048, l_ + 4096); \
} while (0)

#define STGB(kt_) do { \
    const bf16* g_ = gB + (kt_) * 32; \
    bf16* l_ = lds + (((kt_) & 1) << 14) + w * 512; \
    gld16(g_, l_); gld16(g_ + 128 * 2048, l_ + 4096); \
} while (0)

#define LD4(dst_, i0_, base_) do { \
    _Pragma("unroll") for (int i_ = 0; i_ < 4; ++i_) \
        dst_[(i0_) + i_] = *reinterpret_cast<const bf16x8*>((base_) + i_ * 512); \
} while (0)

#define MFMA16(mh_) do { \
    _Pragma("unroll") for (int mi_ = 0; mi_ < 4; ++mi_) \
        _Pragma("unroll") for (int ni_ = 0; ni_ < 4; ++ni_) \
            acc[(mh_) * 4 + mi_][ni_] = __builtin_amdgcn_mfma_f32_16x16x32_bf16( \
                af[(mh_) * 4 + mi_], bq[ni_], acc[(mh_) * 4 + mi_][ni_], 0, 0, 0); \
} while (0)

#define BAR  __builtin_amdgcn_s_barrier()
#define PRI1 __builtin_amdgcn_s_setprio(1)
#define PRI0 __builtin_amdgcn_s_setprio(0)
#define LGK0 asm volatile("s_waitcnt lgkmcnt(0)" ::: "memory")
#define VM4  asm volatile("s_waitcnt vmcnt(4)" ::: "memory")
#define VM0  asm volatile("s_waitcnt vmcnt(0)" ::: "memory")

// one K-tile. cb_ = buf byte.. element offset (0/16384). Stages tile t+2 into
// the SAME buffer (t+2 == t mod 2), which is legal because all waves'
// fragment reads completed before any wave passed BAR (LGK0 precedes BAR).
#define TILE(cb_, SA_, SB_, VM_) do { \
    const bf16* rb_ = lds + (cb_) + boff; \
    const bf16* ra_ = lds + (cb_) + 8192 + aoff; \
    bf16x8 af[8], bq[4]; \
    LD4(af, 0, ra_); \
    LD4(af, 4, ra_ + 2048); \
    LD4(bq, 0, rb_); \
    LGK0; \
    BAR; \
    SA_; \
    PRI1; MFMA16(0); PRI0; \
    SB_; \
    PRI1; MFMA16(1); PRI0; \
    VM_; \
    BAR; \
} while (0)

    // prologue: stage tiles 0 and 1 (8 loads); wait tile0 complete (4 newest =
    // tile1 may stay in flight); barrier so every wave sees tile0.
    STGB(0); STGA(0); STGB(1); STGA(1);
    VM4;
    BAR;

    #pragma unroll 1
    for (int t = 0; t < 61; t += 2) {
        TILE(0,     STGA(t + 2), STGB(t + 2), VM4);
        TILE(16384, STGA(t + 3), STGB(t + 3), VM4);
    }
    // tile 62: nothing left to stage; drain fully so tile 63's data is in.
    TILE(0,     (void)0, (void)0, VM0);
    // tile 63: compute only.
    TILE(16384, (void)0, (void)0, (void)0);

#undef STGA
#undef STGB
#undef LD4
#undef MFMA16
#undef BAR
#undef PRI1
#undef PRI0
#undef LGK0
#undef VM4
#undef VM0
#undef TILE

    #pragma unroll
    for (int mt = 0; mt < 8; ++mt) {
        size_t row = mblk + wm * 128 + mt * 16 + quad * 4;
        #pragma unroll
        for (int nt = 0; nt < 4; ++nt) {
            size_t col = nblk + wn * 64 + nt * 16 + l16;
            #pragma unroll
            for (int r = 0; r < 4; ++r) {
                if (OUT_BF16)
                    reinterpret_cast<bf16*>(Cout)[(row + r) * (size_t)ldc + col] = (bf16)acc[mt][nt][r];
                else
                    reinterpret_cast<float*>(Cout)[(row + r) * (size_t)ldc + col] = acc[mt][nt][r];
            }
        }
    }
}

// ---------------- RoPE cos/sin table: tab[t*32+i] = (cos, sin)(t * 10000^(-i/32))
__global__ void k_tab(float2* __restrict__ tab) {
    int id = blockIdx.x * 256 + threadIdx.x;   // 65536
    int i = id & 31, t = id >> 5;
    float inv = __builtin_amdgcn_exp2f(-(float)i * 0.41524101186092037f);
    float ang = (float)t * inv;
    float s, c;
    __sincosf(ang, &s, &c);
    tab[id] = make_float2(c, s);
}

// ---------------- RoPE apply, vectorized, table-based ------------------------
__global__ void k_rope(bf16* __restrict__ qkv, const float2* __restrict__ tab) {
    int id = blockIdx.x * 256 + threadIdx.x;   // 2^20 threads
    int j   = id & 3;
    int h   = (id >> 2) & 31;
    int sel = (id >> 7) & 1;
    int t   = (id >> 8) & 2047;
    int b   = id >> 19;
    size_t base = ((size_t)(b * T_ + t)) * 6144 + sel * 2048 + h * 64 + j * 8;
    bf16x8 x1 = load8(qkv + base);
    bf16x8 x2 = load8(qkv + base + 32);
    const float2* tp = tab + t * 32 + j * 8;
    bf16x8 o1, o2;
    #pragma unroll
    for (int e = 0; e < 8; e++) {
        float c = tp[e].x, s = tp[e].y;
        float a = (float)x1[e], v = (float)x2[e];
        o1[e] = (bf16)(a * c - v * s);
        o2[e] = (bf16)(v * c + a * s);
    }
    *reinterpret_cast<bf16x8*>(qkv + base)      = o1;
    *reinterpret_cast<bf16x8*>(qkv + base + 32) = o2;
}

// ---------------- v = l1*v1 + l2*v_gemm -> vT [B,H,DH,T] bf16 ----------------
__global__ void k_combinev(const float* __restrict__ v1, const bf16* __restrict__ qkv,
                           const float* __restrict__ l1p, const float* __restrict__ l2p,
                           bf16* __restrict__ vT) {
    __shared__ float tile[64 * 33];
    float l1 = l1p[0], l2 = l2p[0];
    int b = blockIdx.y >> 5, h = blockIdx.y & 31;
    int t0 = blockIdx.x * 32;
    int tid = threadIdx.x;
    int d = tid & 63, tr = tid >> 6;
    #pragma unroll
    for (int i = 0; i < 8; i++) {
        int t = t0 + i * 4 + tr;
        size_t iv1 = ((size_t)(b * T_ + t)) * 2048 + h * 64 + d;
        size_t ivg = ((size_t)(b * T_ + t)) * 6144 + 4096 + h * 64 + d;
        tile[d * 33 + i * 4 + tr] = l1 * v1[iv1] + l2 * (float)qkv[ivg];
    }
    __syncthreads();
    int tl = tid & 31, dr = tid >> 5;
    #pragma unroll
    for (int j = 0; j < 8; j++) {
        int d2 = dr + j * 8;
        vT[((size_t)((b * H_ + h) * 64 + d2)) * T_ + t0 + tl] = (bf16)tile[d2 * 33 + tl];
    }
}

// ---------------- causal flash attention, S^T form ----------------
__global__ __launch_bounds__(256)
void k_attn(const bf16* __restrict__ qkv, const bf16* __restrict__ vT, bf16* __restrict__ o) {
    __shared__ bf16 ldsK[64 * 64];   // [key][dh], swizzled
    __shared__ bf16 ldsV[64 * 64];   // [dh][key], swizzled
    int bx = blockIdx.x;             // 0..15
    int bh = blockIdx.y;
    int b = bh >> 5, h = bh & 31;
    int tid = threadIdx.x;
    int lane = tid & 63, w = tid >> 6;
    int l16 = lane & 15, quad = lane >> 4;

    int rl = lane >> 3, sg = ((lane & 7) ^ rl) * 8;
    const bf16* kgl = qkv + ((size_t)(b * T_) + w * 16 + rl) * 6144 + 2048 + h * 64 + sg;
    const bf16* vgl = vT + ((size_t)bh * DH + w * 16 + rl) * T_ + sg;
    bf16* lKw = ldsK + w * 16 * 64;
    bf16* lVw = ldsV + w * 16 * 64;

    int skey = (quad ^ (l16 & 7)) * 8;            // K read seg, dh 0..31
    int skey2 = ((quad + 4) ^ (l16 & 7)) * 8;     // K read seg, dh 32..63

    #pragma unroll 1
    for (int pass = 0; pass < 2; pass++) {
        int qt = pass ? (31 - bx) : bx;
        int qbase = qt * 64 + w * 16;

        size_t qrow = (size_t)(b * T_ + qbase + l16) * 6144 + h * 64;
        bf16x8 qf[2];
        #pragma unroll
        for (int half = 0; half < 2; half++) {
            bf16x8 v = load8(qkv + qrow + half * 32 + quad * 8);
            #pragma unroll
            for (int e = 0; e < 8; e++) v[e] = (bf16)((float)v[e] * 0.1803368801f);
            qf[half] = v;
        }

        f32x4 accO[4] = {};
        float m_ = -1e30f, pl = 0.f;

        int nkt = qt + 1;
        for (int kt = 0; kt < nkt; kt++) {
            int key0 = kt * 64;
            #pragma unroll
            for (int j = 0; j < 2; j++) {
                gld16(kgl + (size_t)(key0 + j * 8) * 6144, lKw + j * 512);
                gld16(vgl + (size_t)(j * 8) * T_ + key0,   lVw + j * 512);
            }
            __syncthreads();

            bool diag = (kt == qt);
            f32x4 st[4];
            sv4 pk[4];
            #pragma unroll
            for (int ks = 0; ks < 4; ks++) {
                if (!diag || key0 + ks * 16 <= qbase + 15) {
                    bf16x8 kf0 = *reinterpret_cast<bf16x8*>(&ldsK[(ks * 16 + l16) * 64 + skey]);
                    bf16x8 kf1 = *reinterpret_cast<bf16x8*>(&ldsK[(ks * 16 + l16) * 64 + skey2]);
                    f32x4 z = {};
                    z = __builtin_amdgcn_mfma_f32_16x16x32_bf16(kf0, qf[0], z, 0, 0, 0);
                    z = __builtin_amdgcn_mfma_f32_16x16x32_bf16(kf1, qf[1], z, 0, 0, 0);
                    st[ks] = z;
                } else {
                    st[ks] = (f32x4){-3e38f, -3e38f, -3e38f, -3e38f};
                }
            }

            if (diag) {
                int qcol = qbase + l16;
                #pragma unroll
                for (int ks = 0; ks < 4; ks++)
                    #pragma unroll
                    for (int r = 0; r < 4; r++)
                        if (key0 + ks * 16 + quad * 4 + r > qcol) st[ks][r] = -3e38f;
            }

            float mx = st[0][0];
            #pragma unroll
            for (int ks = 0; ks < 4; ks++)
                #pragma unroll
                for (int r = 0; r < 4; r++) mx = fmaxf(mx, st[ks][r]);
            mx = fmaxf(mx, __shfl_xor(mx, 16));
            mx = fmaxf(mx, __shfl_xor(mx, 32));
            if (__any(mx > m_)) {
                float nm = fmaxf(m_, mx);
                float alpha = __builtin_amdgcn_exp2f(m_ - nm);
                m_ = nm;
                pl *= alpha;
                #pragma unroll
                for (int n2 = 0; n2 < 4; n2++) accO[n2] *= alpha;
            }
            float rsum = 0.f;
            #pragma unroll
            for (int ks = 0; ks < 4; ks++) {
                bf16x4 ph;
                #pragma unroll
                for (int r = 0; r < 4; r++) {
                    float p = __builtin_amdgcn_exp2f(st[ks][r] - m_);
                    rsum += p;
                    ph[r] = (bf16)p;
                }
                pk[ks] = __builtin_bit_cast(sv4, ph);
            }
            pl += rsum;

            #pragma unroll
            for (int ks = 0; ks < 4; ks++) {
                if (!diag || key0 + ks * 16 <= qbase + 15) {
                    int svf = ((ks * 2 + (quad >> 1)) ^ (l16 & 7)) * 8 + (quad & 1) * 4;
                    #pragma unroll
                    for (int n2 = 0; n2 < 4; n2++) {
                        sv4 vf = *reinterpret_cast<sv4*>(&ldsV[(n2 * 16 + l16) * 64 + svf]);
                        accO[n2] = __builtin_amdgcn_mfma_f32_16x16x16bf16_1k(
                            vf, pk[ks], accO[n2], 0, 0, 0);
                    }
                }
            }
            __syncthreads();
        }

        float l = pl;
        l += __shfl_xor(l, 16);
        l += __shfl_xor(l, 32);
        float inv = 1.0f / l;
        int query = qbase + l16;
        #pragma unroll
        for (int n2 = 0; n2 < 4; n2++) {
            bf16x4 ov;
            #pragma unroll
            for (int r = 0; r < 4; r++) ov[r] = (bf16)(accO[n2][r] * inv);
            *reinterpret_cast<bf16x4*>(
                &o[(size_t)(b * T_ + query) * DM + h * 64 + n2 * 16 + quad * 4]) = ov;
        }
    }
}

extern "C" void kernel_launch(void* const* d_in, const int* in_sizes, int n_in,
                              void* d_out, int out_size, void* d_ws, size_t ws_size,
                              hipStream_t stream) {
    const float* hs   = (const float*)d_in[0];
    const float* v1   = (const float*)d_in[1];
    const float* lam1 = (const float*)d_in[2];
    const float* Wq   = (const float*)d_in[3];
    const float* Wk   = (const float*)d_in[4];
    const float* Wv   = (const float*)d_in[5];
    const float* Wo   = (const float*)d_in[6];
    const float* lam2 = (const float*)d_in[7];

    char* ws = (char*)d_ws;
    bf16* hs_bf = (bf16*)(ws);                            // 16 MiB (dead after QKV gemm)
    float2* tab = (float2*)(ws);                          // 512 KB, reuses hs_bf region
    bf16* Wcat  = (bf16*)(ws + 16777216);                 // WqT|WkT|WvT, 24 MiB
    bf16* WoT   = (bf16*)(ws + 41943040);                 // 8 MiB
    bf16* qkv   = (bf16*)(ws + 50331648);                 // 4096x6144 bf16 = 48 MiB
    bf16* vT_bf = (bf16*)(ws + 100663296);                // 16 MiB
    bf16* o_bf  = (bf16*)(ws + 117440512);                // 16 MiB -> 128 MiB

    k_convert<<<8192, 256, 0, stream>>>(hs, hs_bf, 2097152);
    k_transposeW<<<dim3(64, 64, 4), dim3(32, 8), 0, stream>>>(
        Wq, Wk, Wv, Wo, Wcat, Wcat + 4194304, Wcat + 8388608, WoT);

    // QKV: M=4096, N=6144, K=2048 -> 24x16 = 384 blocks, 256^2 deep-lead
    k_gemm256<1><<<dim3(24, 16), 512, 0, stream>>>(hs_bf, Wcat, (void*)qkv, 6144);

    k_tab<<<256, 256, 0, stream>>>(tab);                  // hs_bf dead from here
    k_rope<<<4096, 256, 0, stream>>>(qkv, tab);

    k_combinev<<<dim3(64, 64), 256, 0, stream>>>(v1, qkv, lam1, lam2, vT_bf);

    k_attn<<<dim3(16, 64), 256, 0, stream>>>(qkv, vT_bf, o_bf);

    k_gemm<0><<<dim3(16, 32), 256, 0, stream>>>(o_bf, WoT, d_out, 2048);
}

// Round 4
// 430.322 us; speedup vs baseline: 1.0360x; 1.0224x over previous
//
#include <hip/hip_runtime.h>
#include <hip/hip_bf16.h>
#include <math.h>

typedef __bf16 bf16;
typedef __bf16 bf16x8 __attribute__((ext_vector_type(8)));
typedef __bf16 bf16x4 __attribute__((ext_vector_type(4)));
typedef float  f32x4  __attribute__((ext_vector_type(4)));
typedef short  sv4    __attribute__((ext_vector_type(4)));

#define B_  2
#define T_  2048
#define DM  2048
#define H_  32
#define DH  64

__device__ __forceinline__ bf16x8 load8(const bf16* p) {
    return *reinterpret_cast<const bf16x8*>(p);
}

__device__ __forceinline__ void gld16(const bf16* g, bf16* l) {
    __builtin_amdgcn_global_load_lds(
        (const __attribute__((address_space(1))) unsigned int*)g,
        (__attribute__((address_space(3))) unsigned int*)l, 16, 0, 0);
}

// ---------------- convert fp32 -> bf16 ----------------
__global__ void k_convert(const float* __restrict__ in, bf16* __restrict__ out, int n4) {
    int i = blockIdx.x * blockDim.x + threadIdx.x;
    if (i < n4) {
        float4 v = reinterpret_cast<const float4*>(in)[i];
        bf16x4 o;
        o[0] = (bf16)v.x; o[1] = (bf16)v.y; o[2] = (bf16)v.z; o[3] = (bf16)v.w;
        reinterpret_cast<bf16x4*>(out)[i] = o;
    }
}

// ---------------- transpose + convert weights ----------------
__global__ void k_transposeW(const float* __restrict__ Wq, const float* __restrict__ Wk,
                             const float* __restrict__ Wv, const float* __restrict__ Wo,
                             bf16* __restrict__ WqT, bf16* __restrict__ WkT,
                             bf16* __restrict__ WvT, bf16* __restrict__ WoT) {
    const float* in; bf16* out;
    switch (blockIdx.z) {
        case 0: in = Wq; out = WqT; break;
        case 1: in = Wk; out = WkT; break;
        case 2: in = Wv; out = WvT; break;
        default: in = Wo; out = WoT; break;
    }
    __shared__ float tile[32][33];
    int tx = threadIdx.x, ty = threadIdx.y;
    int x0 = blockIdx.x * 32, y0 = blockIdx.y * 32;
    #pragma unroll
    for (int i = 0; i < 4; i++)
        tile[ty + i*8][tx] = in[(size_t)(y0 + ty + i*8) * DM + x0 + tx];
    __syncthreads();
    #pragma unroll
    for (int i = 0; i < 4; i++)
        out[(size_t)(x0 + ty + i*8) * DM + y0 + tx] = (bf16)tile[tx][ty + i*8];
}

// ---------------- m97-style GEMM, XOR-swizzled LDS (conflict-free) -----------
// Kept for the out-projection (M=4096,N=2048 -> 512 blocks of 128x128 fills
// all CUs; a 256^2 tiling would give only 128 blocks = half the chip idle).
template<int OUT_BF16>
__global__ __launch_bounds__(256)
void k_gemm(const bf16* __restrict__ A, const bf16* __restrict__ BT,
            void* __restrict__ Cout, int ldc) {
    constexpr int K = 2048;
    __shared__ bf16 ldsA[128 * 32];
    __shared__ bf16 ldsB[128 * 32];
    int tid = threadIdx.x;
    int lane = tid & 63, w = tid >> 6;
    int l16 = lane & 15, quad = lane >> 4;
    int wm = w >> 1, wn = w & 1;
    int mblk = blockIdx.y * 128, nblk = blockIdx.x * 128;

    f32x4 acc[4][4] = {};

    int sgz = ((lane & 3) ^ ((lane >> 3) & 3)) * 8;      // swizzled global seg
    const bf16* gA = A  + (size_t)(mblk + w * 32 + (lane >> 2)) * K + sgz;
    const bf16* gB = BT + (size_t)(nblk + w * 32 + (lane >> 2)) * K + sgz;
    bf16* lA = ldsA + w * 1024;
    bf16* lB = ldsB + w * 1024;
    int sA = (quad ^ ((l16 >> 1) & 3)) * 8;              // swizzled read seg

    for (int k0 = 0; k0 < K; k0 += 32) {
        gld16(gA + k0,          lA);
        gld16(gA + 16 * K + k0, lA + 512);
        gld16(gB + k0,          lB);
        gld16(gB + 16 * K + k0, lB + 512);
        __syncthreads();
        bf16x8 af[4], bfr[4];
        #pragma unroll
        for (int s = 0; s < 4; s++)
            af[s] = *reinterpret_cast<bf16x8*>(&ldsA[(wm * 64 + s * 16 + l16) * 32 + sA]);
        #pragma unroll
        for (int t = 0; t < 4; t++)
            bfr[t] = *reinterpret_cast<bf16x8*>(&ldsB[(wn * 64 + t * 16 + l16) * 32 + sA]);
        #pragma unroll
        for (int s = 0; s < 4; s++)
            #pragma unroll
            for (int t = 0; t < 4; t++)
                acc[s][t] = __builtin_amdgcn_mfma_f32_16x16x32_bf16(af[s], bfr[t], acc[s][t], 0, 0, 0);
        __syncthreads();
    }

    #pragma unroll
    for (int s = 0; s < 4; s++) {
        int row = mblk + wm * 64 + s * 16 + quad * 4;
        #pragma unroll
        for (int t = 0; t < 4; t++) {
            int col = nblk + wn * 64 + t * 16 + l16;
            #pragma unroll
            for (int r = 0; r < 4; r++) {
                if (OUT_BF16)
                    reinterpret_cast<bf16*>(Cout)[(size_t)(row + r) * ldc + col] = (bf16)acc[s][t][r];
                else
                    reinterpret_cast<float*>(Cout)[(size_t)(row + r) * ldc + col] = acc[s][t][r];
            }
        }
    }
}

// ---------------- 256x256 GEMM, BK=32, 3-BUFFER rotation, 96 KiB LDS --------
// Round-2/3 post-mortem: 2-buffer schedules cap the stage lead at <1 tile ->
// every tile pays an HBM/L2-latency stall at its vmcnt; lgkm-before-barrier
// (round 3) additionally serializes the LDS burst against the MFMA burst.
// Fix: 3-buffer rotation. Tile T reads buf T%3; during T we stage tile T+2
// into buf (T+2)%3 (!= current, != next; holds tile T-1's fully-consumed
// data, barrier-separated -> race-free). vmcnt(4) at tile end keeps only
// T+2's 4 loads outstanding => T+1 GUARANTEED resident, issue-to-wait ~2
// tiles (~2900 cyc >> 900-cyc HBM latency). Never drained in-loop.
// ONE barrier per tile, order {ds_read(T); stage(T+2); vmcnt(4); BAR;
// setprio1; 32 MFMA; setprio0}: the next tile's ds_reads issue while the
// matrix pipe drains this tile's MFMAs -> LDS/MFMA pipe overlap.
// Same XOR seg-swizzle as k_gemm (proven 0 bank conflicts rounds 0-3).
// Dynamic LDS 96 KiB; opt-in attribute is set at .so load time (static
// ctor) -- NEVER inside kernel_launch (graph capture would break).
template<int OUT_BF16>
__global__ __launch_bounds__(512, 2)
void k_gemm256(const bf16* __restrict__ A, const bf16* __restrict__ BT,
               void* __restrict__ Cout, int ldc) {
    constexpr int K = 2048;
    extern __shared__ bf16 lds[];                   // 3 bufs x {B:8192, A:8192} elems
    const int tid  = threadIdx.x;
    const int lane = tid & 63, w = tid >> 6;
    const int l16  = lane & 15, quad = lane >> 4;
    const int wm   = w >> 2, wn = w & 3;
    const size_t mblk = (size_t)blockIdx.y * 256, nblk = (size_t)blockIdx.x * 256;

    f32x4 acc[8][4] = {};

    // staging: thread covers row (tid>>2) (+128 for 2nd load), 16B seg.
    // stored seg = tid&3 -> fetch logical seg (tid&3)^((row>>1)&3).
    const int sg = (((tid & 3) ^ ((tid >> 3) & 3)) << 3);
    const bf16* gA = A  + (mblk + (tid >> 2)) * K + sg;
    const bf16* gB = BT + (nblk + (tid >> 2)) * K + sg;

    // fragment reads: row = base+l16 (base mult of 16), logical seg = quad.
    const int segr = ((quad ^ ((l16 >> 1) & 3)) << 3);
    const int aoff = (wm * 128 + l16) * 32 + segr;  // A region (+8192 in buf)
    const int boff = (wn * 64  + l16) * 32 + segr;  // B region (+0 in buf)

#define STG(kt_, buf_) do { \
    const bf16* ga_ = gA + (kt_) * 32; \
    const bf16* gb_ = gB + (kt_) * 32; \
    bf16* lb_ = lds + (buf_) * 16384 + w * 512; \
    bf16* la_ = lds + (buf_) * 16384 + 8192 + w * 512; \
    gld16(gb_, lb_); gld16(gb_ + 128 * 2048, lb_ + 4096); \
    gld16(ga_, la_); gld16(ga_ + 128 * 2048, la_ + 4096); \
} while (0)

#define BAR  __builtin_amdgcn_s_barrier()
#define PRI1 __builtin_amdgcn_s_setprio(1)
#define PRI0 __builtin_amdgcn_s_setprio(0)
#define VM4  asm volatile("s_waitcnt vmcnt(4)" ::: "memory")
#define VM0  asm volatile("s_waitcnt vmcnt(0)" ::: "memory")

// one K-tile. cb_ = element offset of this tile's buffer (buf*16384).
// reads -> stage(T+2) -> vmcnt -> barrier -> MFMA (acc-only, overlaps next
// tile's reads via pipe queueing; compiler auto-inserts per-use lgkmcnt).
#define TILE(cb_, SG_, VM_) do { \
    const bf16* rb_ = lds + (cb_) + boff; \
    const bf16* ra_ = lds + (cb_) + 8192 + aoff; \
    bf16x8 af[8], bq[4]; \
    _Pragma("unroll") for (int i_ = 0; i_ < 8; ++i_) \
        af[i_] = *reinterpret_cast<const bf16x8*>(ra_ + i_ * 512); \
    _Pragma("unroll") for (int i_ = 0; i_ < 4; ++i_) \
        bq[i_] = *reinterpret_cast<const bf16x8*>(rb_ + i_ * 512); \
    SG_; \
    VM_; \
    BAR; \
    PRI1; \
    _Pragma("unroll") for (int mi_ = 0; mi_ < 8; ++mi_) \
        _Pragma("unroll") for (int ni_ = 0; ni_ < 4; ++ni_) \
            acc[mi_][ni_] = __builtin_amdgcn_mfma_f32_16x16x32_bf16( \
                af[mi_], bq[ni_], acc[mi_][ni_], 0, 0, 0); \
    PRI0; \
} while (0)

    // prologue: stage tiles 0 (buf0) and 1 (buf1); wait tile0 landed
    // (4 newest = tile1's may stay in flight); barrier for visibility.
    STG(0, 0); STG(1, 1);
    VM4;
    BAR;

    #pragma unroll 1
    for (int t = 0; t < 60; t += 3) {
        TILE(0,     STG(t + 2, 2), VM4);
        TILE(16384, STG(t + 3, 0), VM4);
        TILE(32768, STG(t + 4, 1), VM4);
    }
    // tiles 60..63 peeled (60%3==0):
    TILE(0,     STG(62, 2), VM4);
    TILE(16384, STG(63, 0), VM4);
    TILE(32768, (void)0,    VM0);   // drain: 63's loads are ~1 tile old
    TILE(0,     (void)0,    (void)0);

#undef STG
#undef BAR
#undef PRI1
#undef PRI0
#undef VM4
#undef VM0
#undef TILE

    #pragma unroll
    for (int mt = 0; mt < 8; ++mt) {
        size_t row = mblk + wm * 128 + mt * 16 + quad * 4;
        #pragma unroll
        for (int nt = 0; nt < 4; ++nt) {
            size_t col = nblk + wn * 64 + nt * 16 + l16;
            #pragma unroll
            for (int r = 0; r < 4; ++r) {
                if (OUT_BF16)
                    reinterpret_cast<bf16*>(Cout)[(row + r) * (size_t)ldc + col] = (bf16)acc[mt][nt][r];
                else
                    reinterpret_cast<float*>(Cout)[(row + r) * (size_t)ldc + col] = acc[mt][nt][r];
            }
        }
    }
}

// Opt-in to 96 KiB dynamic LDS at .so load time (NOT during graph capture).
namespace {
struct GemmLdsInit {
    GemmLdsInit() {
        (void)hipFuncSetAttribute(
            reinterpret_cast<const void*>(&k_gemm256<1>),
            hipFuncAttributeMaxDynamicSharedMemorySize, 98304);
    }
};
GemmLdsInit g_ldsInit;
}

// ---------------- RoPE cos/sin table: tab[t*32+i] = (cos, sin)(t * 10000^(-i/32))
__global__ void k_tab(float2* __restrict__ tab) {
    int id = blockIdx.x * 256 + threadIdx.x;   // 65536
    int i = id & 31, t = id >> 5;
    float inv = __builtin_amdgcn_exp2f(-(float)i * 0.41524101186092037f);
    float ang = (float)t * inv;
    float s, c;
    __sincosf(ang, &s, &c);
    tab[id] = make_float2(c, s);
}

// ---------------- RoPE apply, vectorized, table-based ------------------------
__global__ void k_rope(bf16* __restrict__ qkv, const float2* __restrict__ tab) {
    int id = blockIdx.x * 256 + threadIdx.x;   // 2^20 threads
    int j   = id & 3;
    int h   = (id >> 2) & 31;
    int sel = (id >> 7) & 1;
    int t   = (id >> 8) & 2047;
    int b   = id >> 19;
    size_t base = ((size_t)(b * T_ + t)) * 6144 + sel * 2048 + h * 64 + j * 8;
    bf16x8 x1 = load8(qkv + base);
    bf16x8 x2 = load8(qkv + base + 32);
    const float2* tp = tab + t * 32 + j * 8;
    bf16x8 o1, o2;
    #pragma unroll
    for (int e = 0; e < 8; e++) {
        float c = tp[e].x, s = tp[e].y;
        float a = (float)x1[e], v = (float)x2[e];
        o1[e] = (bf16)(a * c - v * s);
        o2[e] = (bf16)(v * c + a * s);
    }
    *reinterpret_cast<bf16x8*>(qkv + base)      = o1;
    *reinterpret_cast<bf16x8*>(qkv + base + 32) = o2;
}

// ---------------- v = l1*v1 + l2*v_gemm -> vT [B,H,DH,T] bf16 ----------------
__global__ void k_combinev(const float* __restrict__ v1, const bf16* __restrict__ qkv,
                           const float* __restrict__ l1p, const float* __restrict__ l2p,
                           bf16* __restrict__ vT) {
    __shared__ float tile[64 * 33];
    float l1 = l1p[0], l2 = l2p[0];
    int b = blockIdx.y >> 5, h = blockIdx.y & 31;
    int t0 = blockIdx.x * 32;
    int tid = threadIdx.x;
    int d = tid & 63, tr = tid >> 6;
    #pragma unroll
    for (int i = 0; i < 8; i++) {
        int t = t0 + i * 4 + tr;
        size_t iv1 = ((size_t)(b * T_ + t)) * 2048 + h * 64 + d;
        size_t ivg = ((size_t)(b * T_ + t)) * 6144 + 4096 + h * 64 + d;
        tile[d * 33 + i * 4 + tr] = l1 * v1[iv1] + l2 * (float)qkv[ivg];
    }
    __syncthreads();
    int tl = tid & 31, dr = tid >> 5;
    #pragma unroll
    for (int j = 0; j < 8; j++) {
        int d2 = dr + j * 8;
        vT[((size_t)((b * H_ + h) * 64 + d2)) * T_ + t0 + tl] = (bf16)tile[d2 * 33 + tl];
    }
}

// ---------------- causal flash attention, S^T form ----------------
__global__ __launch_bounds__(256)
void k_attn(const bf16* __restrict__ qkv, const bf16* __restrict__ vT, bf16* __restrict__ o) {
    __shared__ bf16 ldsK[64 * 64];   // [key][dh], swizzled
    __shared__ bf16 ldsV[64 * 64];   // [dh][key], swizzled
    int bx = blockIdx.x;             // 0..15
    int bh = blockIdx.y;
    int b = bh >> 5, h = bh & 31;
    int tid = threadIdx.x;
    int lane = tid & 63, w = tid >> 6;
    int l16 = lane & 15, quad = lane >> 4;

    int rl = lane >> 3, sg = ((lane & 7) ^ rl) * 8;
    const bf16* kgl = qkv + ((size_t)(b * T_) + w * 16 + rl) * 6144 + 2048 + h * 64 + sg;
    const bf16* vgl = vT + ((size_t)bh * DH + w * 16 + rl) * T_ + sg;
    bf16* lKw = ldsK + w * 16 * 64;
    bf16* lVw = ldsV + w * 16 * 64;

    int skey = (quad ^ (l16 & 7)) * 8;            // K read seg, dh 0..31
    int skey2 = ((quad + 4) ^ (l16 & 7)) * 8;     // K read seg, dh 32..63

    #pragma unroll 1
    for (int pass = 0; pass < 2; pass++) {
        int qt = pass ? (31 - bx) : bx;
        int qbase = qt * 64 + w * 16;

        size_t qrow = (size_t)(b * T_ + qbase + l16) * 6144 + h * 64;
        bf16x8 qf[2];
        #pragma unroll
        for (int half = 0; half < 2; half++) {
            bf16x8 v = load8(qkv + qrow + half * 32 + quad * 8);
            #pragma unroll
            for (int e = 0; e < 8; e++) v[e] = (bf16)((float)v[e] * 0.1803368801f);
            qf[half] = v;
        }

        f32x4 accO[4] = {};
        float m_ = -1e30f, pl = 0.f;

        int nkt = qt + 1;
        for (int kt = 0; kt < nkt; kt++) {
            int key0 = kt * 64;
            #pragma unroll
            for (int j = 0; j < 2; j++) {
                gld16(kgl + (size_t)(key0 + j * 8) * 6144, lKw + j * 512);
                gld16(vgl + (size_t)(j * 8) * T_ + key0,   lVw + j * 512);
            }
            __syncthreads();

            bool diag = (kt == qt);
            f32x4 st[4];
            sv4 pk[4];
            #pragma unroll
            for (int ks = 0; ks < 4; ks++) {
                if (!diag || key0 + ks * 16 <= qbase + 15) {
                    bf16x8 kf0 = *reinterpret_cast<bf16x8*>(&ldsK[(ks * 16 + l16) * 64 + skey]);
                    bf16x8 kf1 = *reinterpret_cast<bf16x8*>(&ldsK[(ks * 16 + l16) * 64 + skey2]);
                    f32x4 z = {};
                    z = __builtin_amdgcn_mfma_f32_16x16x32_bf16(kf0, qf[0], z, 0, 0, 0);
                    z = __builtin_amdgcn_mfma_f32_16x16x32_bf16(kf1, qf[1], z, 0, 0, 0);
                    st[ks] = z;
                } else {
                    st[ks] = (f32x4){-3e38f, -3e38f, -3e38f, -3e38f};
                }
            }

            if (diag) {
                int qcol = qbase + l16;
                #pragma unroll
                for (int ks = 0; ks < 4; ks++)
                    #pragma unroll
                    for (int r = 0; r < 4; r++)
                        if (key0 + ks * 16 + quad * 4 + r > qcol) st[ks][r] = -3e38f;
            }

            float mx = st[0][0];
            #pragma unroll
            for (int ks = 0; ks < 4; ks++)
                #pragma unroll
                for (int r = 0; r < 4; r++) mx = fmaxf(mx, st[ks][r]);
            mx = fmaxf(mx, __shfl_xor(mx, 16));
            mx = fmaxf(mx, __shfl_xor(mx, 32));
            if (__any(mx > m_)) {
                float nm = fmaxf(m_, mx);
                float alpha = __builtin_amdgcn_exp2f(m_ - nm);
                m_ = nm;
                pl *= alpha;
                #pragma unroll
                for (int n2 = 0; n2 < 4; n2++) accO[n2] *= alpha;
            }
            float rsum = 0.f;
            #pragma unroll
            for (int ks = 0; ks < 4; ks++) {
                bf16x4 ph;
                #pragma unroll
                for (int r = 0; r < 4; r++) {
                    float p = __builtin_amdgcn_exp2f(st[ks][r] - m_);
                    rsum += p;
                    ph[r] = (bf16)p;
                }
                pk[ks] = __builtin_bit_cast(sv4, ph);
            }
            pl += rsum;

            #pragma unroll
            for (int ks = 0; ks < 4; ks++) {
                if (!diag || key0 + ks * 16 <= qbase + 15) {
                    int svf = ((ks * 2 + (quad >> 1)) ^ (l16 & 7)) * 8 + (quad & 1) * 4;
                    #pragma unroll
                    for (int n2 = 0; n2 < 4; n2++) {
                        sv4 vf = *reinterpret_cast<sv4*>(&ldsV[(n2 * 16 + l16) * 64 + svf]);
                        accO[n2] = __builtin_amdgcn_mfma_f32_16x16x16bf16_1k(
                            vf, pk[ks], accO[n2], 0, 0, 0);
                    }
                }
            }
            __syncthreads();
        }

        float l = pl;
        l += __shfl_xor(l, 16);
        l += __shfl_xor(l, 32);
        float inv = 1.0f / l;
        int query = qbase + l16;
        #pragma unroll
        for (int n2 = 0; n2 < 4; n2++) {
            bf16x4 ov;
            #pragma unroll
            for (int r = 0; r < 4; r++) ov[r] = (bf16)(accO[n2][r] * inv);
            *reinterpret_cast<bf16x4*>(
                &o[(size_t)(b * T_ + query) * DM + h * 64 + n2 * 16 + quad * 4]) = ov;
        }
    }
}

extern "C" void kernel_launch(void* const* d_in, const int* in_sizes, int n_in,
                              void* d_out, int out_size, void* d_ws, size_t ws_size,
                              hipStream_t stream) {
    const float* hs   = (const float*)d_in[0];
    const float* v1   = (const float*)d_in[1];
    const float* lam1 = (const float*)d_in[2];
    const float* Wq   = (const float*)d_in[3];
    const float* Wk   = (const float*)d_in[4];
    const float* Wv   = (const float*)d_in[5];
    const float* Wo   = (const float*)d_in[6];
    const float* lam2 = (const float*)d_in[7];

    char* ws = (char*)d_ws;
    bf16* hs_bf = (bf16*)(ws);                            // 16 MiB (dead after QKV gemm)
    float2* tab = (float2*)(ws);                          // 512 KB, reuses hs_bf region
    bf16* Wcat  = (bf16*)(ws + 16777216);                 // WqT|WkT|WvT, 24 MiB
    bf16* WoT   = (bf16*)(ws + 41943040);                 // 8 MiB
    bf16* qkv   = (bf16*)(ws + 50331648);                 // 4096x6144 bf16 = 48 MiB
    bf16* vT_bf = (bf16*)(ws + 100663296);                // 16 MiB
    bf16* o_bf  = (bf16*)(ws + 117440512);                // 16 MiB -> 128 MiB

    k_convert<<<8192, 256, 0, stream>>>(hs, hs_bf, 2097152);
    k_transposeW<<<dim3(64, 64, 4), dim3(32, 8), 0, stream>>>(
        Wq, Wk, Wv, Wo, Wcat, Wcat + 4194304, Wcat + 8388608, WoT);

    // QKV: M=4096, N=6144, K=2048 -> 24x16 = 384 blocks, 3-buffer pipeline
    k_gemm256<1><<<dim3(24, 16), 512, 98304, stream>>>(hs_bf, Wcat, (void*)qkv, 6144);

    k_tab<<<256, 256, 0, stream>>>(tab);                  // hs_bf dead from here
    k_rope<<<4096, 256, 0, stream>>>(qkv, tab);

    k_combinev<<<dim3(64, 64), 256, 0, stream>>>(v1, qkv, lam1, lam2, vT_bf);

    k_attn<<<dim3(16, 64), 256, 0, stream>>>(qkv, vT_bf, o_bf);

    k_gemm<0><<<dim3(16, 32), 256, 0, stream>>>(o_bf, WoT, d_out, 2048);
}